// Round 1
// baseline (20786.372 us; speedup 1.0000x reference)
//
#include <hip/hip_runtime.h>
#include <cstdint>
#include <cstddef>

// ---------------- problem constants ----------------
#define B_SZ   256
#define T_SZ   512
#define IN_SZ  100
#define H_SZ   275
#define OUT_SZ 100
#define K_TOT  (H_SZ + IN_SZ)     // 375 combined K (recurrent + input)

// ---------------- scan kernel geometry ----------------
#define NGROUP 8                   // batch groups (1 per XCD under bid%8 mapping)
#define NB     32                  // batches per group
#define NMEM   31                  // member blocks per group (31*8=248 < 256 CUs: co-residency slack)
#define GRID1  (NGROUP * NMEM)     // 248
#define NTHR   256

#define WSTR   36                  // padded local gate-rows per member (max 4*9)
#define ZSTR   377                 // odd stride -> conflict-free z reads
#define KUMAX  9

#define WT_FLOATS    (K_TOT * WSTR)   // 13500
#define Z_FLOATS     (NB * ZSTR)      // 12064
#define GATES_FLOATS (NB * WSTR)      // 1152
#define C_FLOATS     (NB * KUMAX)     // 288
#define BIAS_FLOATS  (WSTR)           // 36
#define SMEM1_FLOATS (WT_FLOATS + Z_FLOATS + GATES_FLOATS + C_FLOATS + BIAS_FLOATS)
#define SMEM1_BYTES  (SMEM1_FLOATS * 4)   // 108160 B

// ---------------- out-projection kernel geometry ----------------
#define K2_ROWS 128                // rows per block
#define K2_CHUNK 32                // rows staged per LDS chunk
#define OPAD   112                 // padded out-cols (8 threads * 14 cols)
#define HSTR2  277                 // padded hs row stride in LDS
#define SMEM2_FLOATS (H_SZ * OPAD + K2_CHUNK * HSTR2)  // 30800 + 8864 = 39664
#define SMEM2_BYTES  (SMEM2_FLOATS * 4)                // 158656 B  (< 160 KiB)

__device__ __forceinline__ float sigmoid_f(float v) {
    return 1.0f / (1.0f + __expf(-v));
}
__device__ __forceinline__ float tanh_f(float v) {
    // tanh(x) = 1 - 2/(1+e^{2x}); saturates correctly at +/-inf
    return 1.0f - 2.0f / (1.0f + __expf(2.0f * v));
}

// ===================================================================
// Persistent LSTM scan. group = bid % NGROUP (XCD-colocated members),
// member = bid / NGROUP. Member owns KU hidden units (4*KU gate rows),
// weights [W_hh | W_ih] transposed in LDS, loaded ONCE for all 512 steps.
// Per step: stage z=[h(t-1) | x(t)] -> gates matmul (lane=(batch,k-half),
// wave=9 rows, weight reads are wave-uniform broadcasts) -> shfl reduce ->
// activations + c/h update for owned units -> write h chunk to hs ->
// group spin-barrier on per-(g,t) counter.
// ===================================================================
__global__ __launch_bounds__(NTHR, 1)
void lstm_scan(const float* __restrict__ x, const float* __restrict__ W_ih,
               const float* __restrict__ W_hh, const float* __restrict__ b_ih,
               const float* __restrict__ b_hh, float* __restrict__ hs,
               unsigned int* __restrict__ cnt)
{
    extern __shared__ float smem[];
    float* W_t   = smem;                    // [K_TOT][WSTR] transposed, zero-padded rows
    float* z     = W_t + WT_FLOATS;         // [NB][ZSTR]  z[b][0:275]=h, [275:375]=x
    float* gates = z + Z_FLOATS;            // [NB][WSTR]
    float* c_st  = gates + GATES_FLOATS;    // [NB][KUMAX]
    float* biasl = c_st + C_FLOATS;         // [WSTR]

    const int tid = threadIdx.x;
    const int bid = blockIdx.x;
    const int g   = bid % NGROUP;           // batch group
    const int m   = bid / NGROUP;           // member 0..30
    const int KU  = (m < 27) ? 9 : 8;       // 27*9 + 4*8 = 275 units
    const int u0  = (m < 27) ? (9 * m) : (243 + 8 * (m - 27));
    const int NR  = 4 * KU;                 // live gate rows (32 or 36)
    const int gb  = g * NB;                 // first batch of group

    // ---- one-time: load transposed weight slice + bias into LDS ----
    for (int e = tid; e < K_TOT * WSTR; e += NTHR) {
        int k = e / WSTR;
        int r = e - k * WSTR;
        float v = 0.0f;
        if (r < NR) {
            int gate = r & 3, j = r >> 2;            // row_local = 4*j + gate
            int grow = gate * H_SZ + u0 + j;         // global gate row (i,f,g,o order)
            v = (k < H_SZ) ? W_hh[(size_t)grow * H_SZ + k]
                           : W_ih[(size_t)grow * IN_SZ + (k - H_SZ)];
        }
        W_t[e] = v;
    }
    for (int r = tid; r < WSTR; r += NTHR) {
        float v = 0.0f;
        if (r < NR) {
            int gate = r & 3, j = r >> 2;
            int grow = gate * H_SZ + u0 + j;
            v = b_ih[grow] + b_hh[grow];
        }
        biasl[r] = v;
    }
    for (int e = tid; e < NB * KUMAX; e += NTHR) c_st[e] = 0.0f;

    const int lane = tid & 63;
    const int wave = tid >> 6;
    const int bb   = lane & 31;     // batch within group
    const int kh   = lane >> 5;     // K half
    const int r0   = wave * 9;      // first local row for this wave
    const int k0   = kh ? 188 : 0;
    const int k1   = kh ? K_TOT : 188;

    unsigned int* my_cnt = cnt + (size_t)g * T_SZ;

    for (int t = 0; t < T_SZ; ++t) {
        // ---- stage z = [h(t-1) | x(t)] ----
        if (t == 0) {
            for (int e = tid; e < NB * H_SZ; e += NTHR) {
                int b = e / H_SZ, k = e - b * H_SZ;
                z[b * ZSTR + k] = 0.0f;
            }
        } else {
            for (int e = tid; e < NB * H_SZ; e += NTHR) {
                int b = e / H_SZ, k = e - b * H_SZ;
                z[b * ZSTR + k] = hs[(((size_t)(gb + b)) * T_SZ + (t - 1)) * H_SZ + k];
            }
        }
        for (int e = tid; e < NB * IN_SZ; e += NTHR) {
            int b = e / IN_SZ, k = e - b * IN_SZ;
            z[b * ZSTR + H_SZ + k] = x[(((size_t)(gb + b)) * T_SZ + t) * IN_SZ + k];
        }
        __syncthreads();

        // ---- gates matmul: acc[i] = sum_k z[bb][k] * W_t[k][r0+i] ----
        float acc[9];
        #pragma unroll
        for (int i = 0; i < 9; ++i) acc[i] = 0.0f;
        const float* zrow = z + bb * ZSTR;
        #pragma unroll 4
        for (int k = k0; k < k1; ++k) {
            float zv = zrow[k];
            const float* wrow = W_t + k * WSTR + r0;   // wave-uniform -> LDS broadcast
            #pragma unroll
            for (int i = 0; i < 9; ++i)
                acc[i] = fmaf(zv, wrow[i], acc[i]);
        }
        // combine the two K halves (lane ^ 32)
        #pragma unroll
        for (int i = 0; i < 9; ++i)
            acc[i] += __shfl_xor(acc[i], 32);
        if (kh == 0) {
            #pragma unroll
            for (int i = 0; i < 9; ++i) {
                int r = r0 + i;
                if (r < NR) gates[bb * WSTR + r] = acc[i] + biasl[r];
            }
        }
        __syncthreads();

        // ---- activations + state update + h write (owned units only) ----
        for (int p = tid; p < NB * KU; p += NTHR) {
            int b = p / KU, j = p - b * KU;
            float gi = gates[b * WSTR + 4 * j + 0];
            float gf = gates[b * WSTR + 4 * j + 1];
            float gg = gates[b * WSTR + 4 * j + 2];
            float go = gates[b * WSTR + 4 * j + 3];
            float si = sigmoid_f(gi);
            float sf = sigmoid_f(gf);
            float tg = tanh_f(gg);
            float so = sigmoid_f(go);
            float c  = sf * c_st[b * KUMAX + j] + si * tg;
            c_st[b * KUMAX + j] = c;
            float h  = so * tanh_f(c);
            hs[(((size_t)(gb + b)) * T_SZ + t) * H_SZ + (u0 + j)] = h;
        }
        __syncthreads();   // all hs writes of this block issued & drained (vmcnt) before signal

        // ---- group barrier: one-shot counter per (g,t) ----
        if (tid == 0) {
            __threadfence();
            __hip_atomic_fetch_add(my_cnt + t, 1u, __ATOMIC_RELEASE, __HIP_MEMORY_SCOPE_AGENT);
            while (__hip_atomic_load(my_cnt + t, __ATOMIC_ACQUIRE, __HIP_MEMORY_SCOPE_AGENT) < NMEM)
                __builtin_amdgcn_s_sleep(2);
        }
        __syncthreads();   // releases block; z restage next iter is safe (after barrier)
    }
}

// ===================================================================
// Output projection: out[row][o] = hs[row][:] . W_out[o][:] + b_out[o]
// row = b*T + t (hs and out share this flattening). W_out^T staged in LDS
// (padded to OPAD cols), hs staged in 32-row chunks.
// thread = (r_t = tid>>3, oc = tid&7): 1 row x 14 cols.
// ===================================================================
__global__ __launch_bounds__(256, 1)
void out_proj(const float* __restrict__ hs, const float* __restrict__ W_out,
              const float* __restrict__ b_out, float* __restrict__ out)
{
    extern __shared__ float smem[];
    float* wt = smem;                 // [H_SZ][OPAD] = W_out^T (pad cols unused->garbage ok, masked on write)
    float* ht = wt + H_SZ * OPAD;     // [K2_CHUNK][HSTR2]

    const int tid = threadIdx.x;
    const size_t row_base = (size_t)blockIdx.x * K2_ROWS;

    for (int e = tid; e < OUT_SZ * H_SZ; e += 256) {
        int o = e / H_SZ, k = e - o * H_SZ;
        wt[k * OPAD + o] = W_out[e];
    }
    const int r_t = tid >> 3;   // 0..31
    const int oc  = tid & 7;    // 0..7 -> cols [oc*14, oc*14+14)
    float bias[14];
    #pragma unroll
    for (int j = 0; j < 14; ++j) {
        int o = oc * 14 + j;
        bias[j] = (o < OUT_SZ) ? b_out[o] : 0.0f;
    }
    __syncthreads();

    for (int chunk = 0; chunk < K2_ROWS / K2_CHUNK; ++chunk) {
        size_t rb = row_base + (size_t)chunk * K2_CHUNK;
        for (int e = tid; e < K2_CHUNK * H_SZ; e += 256) {
            int r = e / H_SZ, k = e - r * H_SZ;
            ht[r * HSTR2 + k] = hs[(rb + r) * (size_t)H_SZ + k];
        }
        __syncthreads();

        float acc[14];
        #pragma unroll
        for (int j = 0; j < 14; ++j) acc[j] = bias[j];
        const float* hrow  = ht + r_t * HSTR2;
        const float* wbase = wt + oc * 14;
        for (int k = 0; k < H_SZ; ++k) {
            float hv = hrow[k];                       // 8-lane same-addr broadcast
            const float* wk = wbase + k * OPAD;       // 8B-aligned
            #pragma unroll
            for (int j = 0; j < 7; ++j) {
                float2 w2 = *reinterpret_cast<const float2*>(wk + 2 * j);
                acc[2 * j]     = fmaf(hv, w2.x, acc[2 * j]);
                acc[2 * j + 1] = fmaf(hv, w2.y, acc[2 * j + 1]);
            }
        }
        size_t orow = (rb + r_t) * (size_t)OUT_SZ;
        #pragma unroll
        for (int j = 0; j < 14; ++j) {
            int o = oc * 14 + j;
            if (o < OUT_SZ) out[orow + o] = acc[j];
        }
        __syncthreads();   // before restaging ht
    }
}

// ===================================================================
extern "C" void kernel_launch(void* const* d_in, const int* in_sizes, int n_in,
                              void* d_out, int out_size, void* d_ws, size_t ws_size,
                              hipStream_t stream)
{
    const float* x     = (const float*)d_in[0];
    const float* W_ih  = (const float*)d_in[1];
    const float* W_hh  = (const float*)d_in[2];
    const float* b_ih  = (const float*)d_in[3];
    const float* b_hh  = (const float*)d_in[4];
    const float* W_out = (const float*)d_in[5];
    const float* b_out = (const float*)d_in[6];
    float* out = (float*)d_out;

    // ws layout: hs [B][T][H] fp32 (144,179,200 B) | cnt [NGROUP][T] u32 (16 KiB)
    float* hs = (float*)d_ws;
    const size_t hs_bytes = (size_t)B_SZ * T_SZ * H_SZ * sizeof(float);
    unsigned int* cnt = (unsigned int*)((char*)d_ws + hs_bytes);
    const size_t cnt_bytes = (size_t)NGROUP * T_SZ * sizeof(unsigned int);

    // opt-in to >64 KiB dynamic LDS (idempotent, host-side, capture-safe)
    hipFuncSetAttribute((const void*)lstm_scan, hipFuncAttributeMaxDynamicSharedMemorySize, SMEM1_BYTES);
    hipFuncSetAttribute((const void*)out_proj, hipFuncAttributeMaxDynamicSharedMemorySize, SMEM2_BYTES);

    // zero one-shot barrier counters every launch (ws is re-poisoned by harness)
    hipMemsetAsync(cnt, 0, cnt_bytes, stream);

    hipLaunchKernelGGL(lstm_scan, dim3(GRID1), dim3(NTHR), SMEM1_BYTES, stream,
                       x, W_ih, W_hh, b_ih, b_hh, hs, cnt);

    hipLaunchKernelGGL(out_proj, dim3((B_SZ * T_SZ) / K2_ROWS), dim3(256), SMEM2_BYTES, stream,
                       hs, W_out, b_out, out);
}